// Round 1
// baseline (195.866 us; speedup 1.0000x reference)
//
#include <hip/hip_runtime.h>
#include <hip/hip_bf16.h>
#include <math.h>

// Problem constants (fixed by setup_inputs)
#define M_TOT 2
#define N_TOT 4096
#define DZ    64
#define G_TOT 16384

// Tiling
#define BG      128   // grid points per block (8 waves x M=16)
#define BN      32    // n per K-step (one MFMA K)
#define THREADS 512
#define ZSTR_B  80    // bytes per zT row: 32 bf16 = 64B + 16B pad (16B aligned, 2-way bank alias = free)

typedef __attribute__((ext_vector_type(8))) short short8;  // 8 bf16 (4 VGPRs) MFMA A/B frag
typedef __attribute__((ext_vector_type(4))) float f32x4;   // MFMA C/D frag
typedef __attribute__((ext_vector_type(4))) int   int4v;

__global__ __launch_bounds__(THREADS, 2)
void setconv_kernel(const float* __restrict__ x,       // [2][4096][2]
                    const float* __restrict__ z,       // [2][4096][64]
                    const float* __restrict__ x_grid,  // [2][16384][2]
                    const float* __restrict__ z_grid,  // [2][16384][64]
                    const float* __restrict__ lsp,     // [2]
                    float* __restrict__ out)           // [2][16384][64]
{
    __shared__ __align__(16) float kxS[BN];
    __shared__ __align__(16) float kyS[BN];
    __shared__ __align__(16) float hkS[BN];
    __shared__ __align__(16) unsigned char zT[DZ * ZSTR_B];  // bf16 zT[dz][n]

    const int tid  = threadIdx.x;
    const int wave = tid >> 6;
    const int lane = tid & 63;
    const int quad = lane >> 4;
    const int l16  = lane & 15;

    const int mb    = blockIdx.y;
    const int gbase = blockIdx.x * BG;

    const float LOG2E = 1.44269504088896340736f;
    // lengthscale = 1e-5 + softplus(param), per input dim (uniform, computed per thread)
    const float inv0 = 1.0f / (1e-5f + log1pf(__expf(lsp[0])));
    const float inv1 = 1.0f / (1e-5f + log1pf(__expf(lsp[1])));

    // Per-lane q-data: A-frag row is m = lane&15 for ALL 8 k-elements, so each
    // lane only ever needs ONE grid point's data. log2e folded in so the
    // per-weight exp is a raw v_exp_f32 (exp2).
    const int   grow = gbase + wave * 16 + l16;
    const float qx   = x_grid[(size_t)(mb * G_TOT + grow) * 2 + 0] * inv0;
    const float qy   = x_grid[(size_t)(mb * G_TOT + grow) * 2 + 1] * inv1;
    const float qxL  = LOG2E * qx;
    const float qyL  = LOG2E * qy;
    const float hq   = -0.5f * LOG2E * (qx * qx + qy * qy);

    f32x4 acc[4];
#pragma unroll
    for (int i = 0; i < 4; i++) acc[i] = (f32x4){0.f, 0.f, 0.f, 0.f};

    for (int n0 = 0; n0 < N_TOT; n0 += BN) {
        __syncthreads();  // WAR: previous iteration's frag reads before restage

        // --- stage k-tile (32 points: kx, ky, -0.5*log2e*||k||^2) ---
        if (tid < BN) {
            const float kx = x[(size_t)(mb * N_TOT + n0 + tid) * 2 + 0] * inv0;
            const float ky = x[(size_t)(mb * N_TOT + n0 + tid) * 2 + 1] * inv1;
            kxS[tid] = kx;
            kyS[tid] = ky;
            hkS[tid] = -0.5f * LOG2E * (kx * kx + ky * ky);
        }

        // --- stage z-tile transposed to bf16: zT[dz][n] (B-operand layout) ---
        // 32n x 64dz; thread t handles n-pair (2*n2, 2*n2+1) x 4 dz values,
        // packing each dz row's two n into one b32 LDS write.
        if (tid < 256) {
            const int dzg = tid >> 4;   // 0..15 (dz group of 4)
            const int n2  = tid & 15;   // 0..15 (n pair)
            const float* zp = z + (size_t)(mb * N_TOT + n0 + 2 * n2) * DZ + dzg * 4;
            const float4 a = *(const float4*)zp;        // n even
            const float4 b = *(const float4*)(zp + DZ); // n odd
            const float av[4] = {a.x, a.y, a.z, a.w};
            const float bv[4] = {b.x, b.y, b.z, b.w};
#pragma unroll
            for (int i = 0; i < 4; i++) {
                const unsigned int lo = __float_as_uint(av[i]) + 0x8000u;  // round-half-up to bf16
                const unsigned int hi = __float_as_uint(bv[i]) + 0x8000u;
                const unsigned int p  = __builtin_amdgcn_perm(hi, lo, 0x07060302u);
                *(unsigned int*)(zT + (dzg * 4 + i) * ZSTR_B + n2 * 4) = p;
            }
        }
        __syncthreads();

        // --- k-data for this lane's 8 k-slots (n = quad*8 + j), quad-broadcast LDS reads ---
        const int nq = quad * 8;
        const float4 kxa = *(const float4*)&kxS[nq];
        const float4 kxb = *(const float4*)&kxS[nq + 4];
        const float4 kya = *(const float4*)&kyS[nq];
        const float4 kyb = *(const float4*)&kyS[nq + 4];
        const float4 hka = *(const float4*)&hkS[nq];
        const float4 hkb = *(const float4*)&hkS[nq + 4];
        const float kxr[8] = {kxa.x, kxa.y, kxa.z, kxa.w, kxb.x, kxb.y, kxb.z, kxb.w};
        const float kyr[8] = {kya.x, kya.y, kya.z, kya.w, kyb.x, kyb.y, kyb.z, kyb.w};
        const float hkr[8] = {hka.x, hka.y, hka.z, hka.w, hkb.x, hkb.y, hkb.z, hkb.w};

        // --- weights directly in A-frag layout: A[m=lane&15][k=quad*8+j] ---
        unsigned int aw[4];
#pragma unroll
        for (int jp = 0; jp < 4; jp++) {
            const float s0 = (hq + hkr[2 * jp])     + (qxL * kxr[2 * jp]     + qyL * kyr[2 * jp]);
            const float s1 = (hq + hkr[2 * jp + 1]) + (qxL * kxr[2 * jp + 1] + qyL * kyr[2 * jp + 1]);
            const unsigned int w0 = __float_as_uint(__builtin_amdgcn_exp2f(s0)) + 0x8000u;
            const unsigned int w1 = __float_as_uint(__builtin_amdgcn_exp2f(s1)) + 0x8000u;
            aw[jp] = __builtin_amdgcn_perm(w1, w0, 0x07060302u);
        }
        const int4v  awv   = {(int)aw[0], (int)aw[1], (int)aw[2], (int)aw[3]};
        const short8 afrag = __builtin_bit_cast(short8, awv);

        // --- B-frags from LDS + MFMA over the 4 dz tiles ---
#pragma unroll
        for (int nt = 0; nt < 4; nt++) {
            const short8 bfrag = *(const short8*)(zT + (size_t)(nt * 16 + l16) * ZSTR_B + quad * 16);
            acc[nt] = __builtin_amdgcn_mfma_f32_16x16x32_bf16(afrag, bfrag, acc[nt], 0, 0, 0);
        }
    }

    // --- epilogue: C/D layout col = lane&15 (dz), row = quad*4 + reg (g) ---
    const int gout = gbase + wave * 16 + quad * 4;
#pragma unroll
    for (int nt = 0; nt < 4; nt++) {
#pragma unroll
        for (int r = 0; r < 4; r++) {
            const size_t idx = (size_t)(mb * G_TOT + gout + r) * DZ + nt * 16 + l16;
            out[idx] = z_grid[idx] + acc[nt][r];
        }
    }
}

extern "C" void kernel_launch(void* const* d_in, const int* in_sizes, int n_in,
                              void* d_out, int out_size, void* d_ws, size_t ws_size,
                              hipStream_t stream) {
    const float* x   = (const float*)d_in[0];
    const float* z   = (const float*)d_in[1];
    const float* xg  = (const float*)d_in[2];
    const float* zgr = (const float*)d_in[3];
    const float* lsp = (const float*)d_in[4];
    dim3 grid(G_TOT / BG, M_TOT);
    setconv_kernel<<<grid, THREADS, 0, stream>>>(x, z, xg, zgr, lsp, (float*)d_out);
}

// Round 2
// 127.214 us; speedup vs baseline: 1.5397x; 1.5397x over previous
//
#include <hip/hip_runtime.h>
#include <hip/hip_bf16.h>
#include <math.h>

// Problem constants (fixed by setup_inputs)
#define M_TOT 2
#define N_TOT 4096
#define DZ    64
#define G_TOT 16384

// Tiling
#define BG      128   // grid points per block = 8 waves x 16 rows
#define BN      64    // n per pipelined iteration (two MFMA K-steps)
#define THREADS 512
#define NSPLIT  2     // n-range split across grid.z (atomic output combine)
#define NCHUNK  (N_TOT / NSPLIT)
#define ITERS   (NCHUNK / BN)
#define ZROW_B  144   // bytes per zT row: 64 bf16 = 128B + 16B pad (keeps b128 reads 16B-aligned,
                      // bank = 4*l16 + 4*quad + c -> conflict-free per 8-lane group)

typedef __attribute__((ext_vector_type(8))) short short8;  // 8 bf16 (4 VGPRs) MFMA A/B frag
typedef __attribute__((ext_vector_type(4))) float f32x4;   // MFMA C/D frag
typedef __attribute__((ext_vector_type(4))) int   int4v;

__device__ __forceinline__ unsigned int pack_bf16_pair(float even, float odd) {
    const unsigned int lo = __float_as_uint(even) + 0x8000u;  // round-half-up to bf16
    const unsigned int hi = __float_as_uint(odd)  + 0x8000u;
    return __builtin_amdgcn_perm(hi, lo, 0x07060302u);        // [lo[31:16], hi[31:16]]
}

__global__ __launch_bounds__(THREADS, 2)
void setconv_kernel(const float* __restrict__ x,       // [2][4096][2]
                    const float* __restrict__ z,       // [2][4096][64]
                    const float* __restrict__ x_grid,  // [2][16384][2]
                    const float* __restrict__ lsp,     // [2]
                    float* __restrict__ out)           // [2][16384][64] pre-initialized to z_grid
{
    // Double-buffered LDS: one barrier per K-iteration.
    __shared__ __align__(16) unsigned char zT[2][DZ * ZROW_B];  // bf16 zT[dz][n], n-pairs packed
    __shared__ __align__(16) float kxS[2][BN];
    __shared__ __align__(16) float kyS[2][BN];
    __shared__ __align__(16) float hkS[2][BN];

    const int tid  = threadIdx.x;
    const int wave = tid >> 6;
    const int lane = tid & 63;
    const int quad = lane >> 4;
    const int l16  = lane & 15;

    const int mb    = blockIdx.y;
    const int gbase = blockIdx.x * BG;
    const int nbase = blockIdx.z * NCHUNK;

    const float LOG2E = 1.44269504088896340736f;
    const float inv0 = 1.0f / (1e-5f + log1pf(__expf(lsp[0])));
    const float inv1 = 1.0f / (1e-5f + log1pf(__expf(lsp[1])));

    // Per-lane q-data (A-frag row m = lane&15 for all 8 k-slots of a K-step).
    const int   grow = gbase + wave * 16 + l16;
    const float qx   = x_grid[(size_t)(mb * G_TOT + grow) * 2 + 0] * inv0;
    const float qy   = x_grid[(size_t)(mb * G_TOT + grow) * 2 + 1] * inv1;
    const float qxL  = LOG2E * qx;
    const float qyL  = LOG2E * qy;
    const float hq   = -0.5f * LOG2E * (qx * qx + qy * qy);

    // Staging assignment: thread -> (dz group of 4, n-pair). Consecutive lanes cover
    // consecutive dz -> 256B-contiguous coalesced global float4 loads.
    const int sdzg = tid & 15;   // dz group: dz = sdzg*4 .. +3
    const int snp  = tid >> 4;   // n-pair: n = 2*snp, 2*snp+1   (0..31)
    const float* zb = z + (size_t)mb * N_TOT * DZ + sdzg * 4;

    f32x4 acc[4];
#pragma unroll
    for (int i = 0; i < 4; i++) acc[i] = (f32x4){0.f, 0.f, 0.f, 0.f};

    // ---- prologue: fetch tile 0, stage into buf 0 ----
    float4 za, zbv;
    float2 kraw;
    {
        const float* zp = zb + (size_t)(nbase + 2 * snp) * DZ;
        za  = *(const float4*)zp;
        zbv = *(const float4*)(zp + DZ);
        if (tid < BN) kraw = *(const float2*)(x + (size_t)(mb * N_TOT + nbase + tid) * 2);
    }
    {
        const float av[4] = {za.x, za.y, za.z, za.w};
        const float bv[4] = {zbv.x, zbv.y, zbv.z, zbv.w};
#pragma unroll
        for (int i = 0; i < 4; i++)
            *(unsigned int*)(&zT[0][(sdzg * 4 + i) * ZROW_B + snp * 4]) = pack_bf16_pair(av[i], bv[i]);
        if (tid < BN) {
            const float kx = kraw.x * inv0, ky = kraw.y * inv1;
            kxS[0][tid] = kx; kyS[0][tid] = ky;
            hkS[0][tid] = -0.5f * LOG2E * (kx * kx + ky * ky);
        }
    }
    __syncthreads();

    for (int t = 0; t < ITERS; t++) {
        const int cur = t & 1, nxt = cur ^ 1;

        // ---- issue next tile's global loads (latency hidden under compute) ----
        if (t + 1 < ITERS) {
            const int nb1 = nbase + (t + 1) * BN;
            const float* zp = zb + (size_t)(nb1 + 2 * snp) * DZ;
            za  = *(const float4*)zp;
            zbv = *(const float4*)(zp + DZ);
            if (tid < BN) kraw = *(const float2*)(x + (size_t)(mb * N_TOT + nb1 + tid) * 2);
        }

        // ---- compute tile t from buf[cur] ----
#pragma unroll
        for (int kc = 0; kc < 2; kc++) {
            const int nq = kc * 32 + quad * 8;
            const float4 kxa = *(const float4*)&kxS[cur][nq];
            const float4 kxb = *(const float4*)&kxS[cur][nq + 4];
            const float4 kya = *(const float4*)&kyS[cur][nq];
            const float4 kyb = *(const float4*)&kyS[cur][nq + 4];
            const float4 hka = *(const float4*)&hkS[cur][nq];
            const float4 hkb = *(const float4*)&hkS[cur][nq + 4];
            const float kxr[8] = {kxa.x, kxa.y, kxa.z, kxa.w, kxb.x, kxb.y, kxb.z, kxb.w};
            const float kyr[8] = {kya.x, kya.y, kya.z, kya.w, kyb.x, kyb.y, kyb.z, kyb.w};
            const float hkr[8] = {hka.x, hka.y, hka.z, hka.w, hkb.x, hkb.y, hkb.z, hkb.w};

            unsigned int aw[4];
#pragma unroll
            for (int jp = 0; jp < 4; jp++) {
                const float s0 = (hq + hkr[2 * jp])     + (qxL * kxr[2 * jp]     + qyL * kyr[2 * jp]);
                const float s1 = (hq + hkr[2 * jp + 1]) + (qxL * kxr[2 * jp + 1] + qyL * kyr[2 * jp + 1]);
                aw[jp] = pack_bf16_pair(__builtin_amdgcn_exp2f(s0), __builtin_amdgcn_exp2f(s1));
            }
            const int4v  awv   = {(int)aw[0], (int)aw[1], (int)aw[2], (int)aw[3]};
            const short8 afrag = __builtin_bit_cast(short8, awv);

#pragma unroll
            for (int nt = 0; nt < 4; nt++) {
                const short8 bfrag =
                    *(const short8*)(&zT[cur][(nt * 16 + l16) * ZROW_B + kc * 64 + quad * 16]);
                acc[nt] = __builtin_amdgcn_mfma_f32_16x16x32_bf16(afrag, bfrag, acc[nt], 0, 0, 0);
            }
        }

        // ---- stage next tile into buf[nxt]; single barrier per iteration ----
        if (t + 1 < ITERS) {
            const float av[4] = {za.x, za.y, za.z, za.w};
            const float bv[4] = {zbv.x, zbv.y, zbv.z, zbv.w};
#pragma unroll
            for (int i = 0; i < 4; i++)
                *(unsigned int*)(&zT[nxt][(sdzg * 4 + i) * ZROW_B + snp * 4]) = pack_bf16_pair(av[i], bv[i]);
            if (tid < BN) {
                const float kx = kraw.x * inv0, ky = kraw.y * inv1;
                kxS[nxt][tid] = kx; kyS[nxt][tid] = ky;
                hkS[nxt][tid] = -0.5f * LOG2E * (kx * kx + ky * ky);
            }
            __syncthreads();
        }
    }

    // ---- epilogue: C/D layout col = lane&15 (dz), row = quad*4 + reg (g) ----
    // out pre-initialized to z_grid; both n-splits combine via device-scope fp32 atomics.
    const int gout = gbase + wave * 16 + quad * 4;
#pragma unroll
    for (int nt = 0; nt < 4; nt++) {
#pragma unroll
        for (int r = 0; r < 4; r++) {
            const size_t idx = (size_t)(mb * G_TOT + gout + r) * DZ + nt * 16 + l16;
            atomicAdd(&out[idx], acc[nt][r]);
        }
    }
}

extern "C" void kernel_launch(void* const* d_in, const int* in_sizes, int n_in,
                              void* d_out, int out_size, void* d_ws, size_t ws_size,
                              hipStream_t stream) {
    const float* x   = (const float*)d_in[0];
    const float* z   = (const float*)d_in[1];
    const float* xg  = (const float*)d_in[2];
    const float* zgr = (const float*)d_in[3];
    const float* lsp = (const float*)d_in[4];
    float* out = (float*)d_out;

    // out = z_grid, then kernel atomically accumulates both n-splits.
    hipMemcpyAsync(out, zgr, sizeof(float) * (size_t)M_TOT * G_TOT * DZ,
                   hipMemcpyDeviceToDevice, stream);

    dim3 grid(G_TOT / BG, M_TOT, NSPLIT);
    setconv_kernel<<<grid, THREADS, 0, stream>>>(x, z, xg, lsp, out);
}

// Round 3
// 125.807 us; speedup vs baseline: 1.5569x; 1.0112x over previous
//
#include <hip/hip_runtime.h>
#include <hip/hip_bf16.h>
#include <math.h>

// Problem constants (fixed by setup_inputs)
#define M_TOT 2
#define N_TOT 4096
#define DZ    64
#define G_TOT 16384

// Tiling: 256-thread blocks, 4 waves, each wave owns 32 g-rows (two A-frags).
#define BG      128
#define BN      64
#define THREADS 256
#define NSPLIT  2
#define NCHUNK  (N_TOT / NSPLIT)   // 2048
#define ITERS   (NCHUNK / BN)      // 32
// zT: bf16 [dz=64][n=64], row = 128 B (no pad). Bank conflicts handled by an
// XOR swizzle of the 16B block index: physical_block = logical_block ^ ((row>>2)&7).
// Swizzle permutes only block position (k-order inside each 16B block preserved),
// so MFMA A/B k-correspondence is unaffected.
#define ZROW_B  128
#define ZT_B    (DZ * ZROW_B)      // 8192
#define KX_OFS  ZT_B               // 8192
#define KY_OFS  (KX_OFS + BN * 4)  // 8448
#define HK_OFS  (KY_OFS + BN * 4)  // 8704
#define BUF_B   (HK_OFS + BN * 4)  // 8960 bytes per pipeline buffer

typedef __attribute__((ext_vector_type(8))) short short8;  // 8 bf16 MFMA A/B frag
typedef __attribute__((ext_vector_type(4))) float f32x4;   // MFMA C/D frag
typedef __attribute__((ext_vector_type(4))) int   int4v;

__device__ __forceinline__ unsigned int pack_bf16_pair(float even, float odd) {
    const unsigned int lo = __float_as_uint(even) + 0x8000u;  // round-half-up to bf16
    const unsigned int hi = __float_as_uint(odd)  + 0x8000u;
    return __builtin_amdgcn_perm(hi, lo, 0x07060302u);        // [lo[31:16], hi[31:16]]
}

// out = z_grid (replaces the ~60us serialized SDMA hipMemcpyAsync with a ~3us kernel)
__global__ __launch_bounds__(256)
void init_out(const float4* __restrict__ zg, float4* __restrict__ out) {
    const int i = blockIdx.x * 256 + threadIdx.x;
    out[i] = zg[i];
}

__global__ __launch_bounds__(THREADS, 2)
void setconv_kernel(const float* __restrict__ x,       // [2][4096][2]
                    const float* __restrict__ z,       // [2][4096][64]
                    const float* __restrict__ x_grid,  // [2][16384][2]
                    const float* __restrict__ lsp,     // [2]
                    float* __restrict__ out)           // [2][16384][64] = z_grid (init_out)
{
    __shared__ __align__(16) unsigned char lds[2 * BUF_B];

    const int tid  = threadIdx.x;
    const int wave = tid >> 6;
    const int lane = tid & 63;
    const int quad = lane >> 4;
    const int l16  = lane & 15;

    const int mb    = blockIdx.y;
    const int gbase = blockIdx.x * BG;
    const int nbase = blockIdx.z * NCHUNK;

    const float LOG2E = 1.44269504088896340736f;
    const float inv0 = 1.0f / (1e-5f + log1pf(__expf(lsp[0])));
    const float inv1 = 1.0f / (1e-5f + log1pf(__expf(lsp[1])));

    // Two row-groups per wave: rows wave*32 + {l16, 16+l16}.
    float qxL[2], qyL[2], hq[2];
#pragma unroll
    for (int g = 0; g < 2; g++) {
        const int grow = gbase + wave * 32 + g * 16 + l16;
        const float2 qraw = *(const float2*)&x_grid[(size_t)(mb * G_TOT + grow) * 2];
        const float qx = qraw.x * inv0, qy = qraw.y * inv1;
        qxL[g] = LOG2E * qx;
        qyL[g] = LOG2E * qy;
        hq[g]  = -0.5f * LOG2E * (qx * qx + qy * qy);
    }

    // Staging assignment: sdzg = dz-group (consecutive lanes -> consecutive dz ->
    // 256B-coalesced global float4 loads), snq = n-quad (4 n per thread).
    const int sdzg = tid & 15;
    const int snq  = tid >> 4;
    const float* zb = z + (size_t)mb * N_TOT * DZ + sdzg * 4;
    // LDS write base (rows d = 4*sdzg+i, logical words {2snq,2snq+1} at swizzled block)
    const unsigned wr_off = (unsigned)(sdzg * 4 * ZROW_B)
                          + (unsigned)((((snq >> 1) ^ (sdzg & 7)) * 16) + (snq & 1) * 8);

    f32x4 acc[2][4];
#pragma unroll
    for (int g = 0; g < 2; g++)
#pragma unroll
        for (int i = 0; i < 4; i++) acc[g][i] = (f32x4){0.f, 0.f, 0.f, 0.f};

    auto stage = [&](unsigned dst, const float4* zf, float2 kraw) {
        const float a0[4] = {zf[0].x, zf[0].y, zf[0].z, zf[0].w};
        const float a1[4] = {zf[1].x, zf[1].y, zf[1].z, zf[1].w};
        const float a2[4] = {zf[2].x, zf[2].y, zf[2].z, zf[2].w};
        const float a3[4] = {zf[3].x, zf[3].y, zf[3].z, zf[3].w};
#pragma unroll
        for (int i = 0; i < 4; i++) {
            uint2 w;
            w.x = pack_bf16_pair(a0[i], a1[i]);
            w.y = pack_bf16_pair(a2[i], a3[i]);
            *(uint2*)(lds + dst + wr_off + i * ZROW_B) = w;
        }
        if (tid < BN) {
            const float kx = kraw.x * inv0, ky = kraw.y * inv1;
            *(float*)(lds + dst + KX_OFS + tid * 4) = kx;
            *(float*)(lds + dst + KY_OFS + tid * 4) = ky;
            *(float*)(lds + dst + HK_OFS + tid * 4) = -0.5f * LOG2E * (kx * kx + ky * ky);
        }
    };

    // ---- prologue: fetch + stage tile 0 into buffer 0 ----
    {
        float4 zf[4];
        float2 kraw = {0.f, 0.f};
        const float* zp = zb + (size_t)(nbase + snq * 4) * DZ;
#pragma unroll
        for (int j = 0; j < 4; j++) zf[j] = *(const float4*)(zp + j * DZ);
        if (tid < BN) kraw = *(const float2*)(x + (size_t)(mb * N_TOT + nbase + tid) * 2);
        stage(0u, zf, kraw);
    }
    __syncthreads();

    const unsigned rb_base = (unsigned)(l16 * ZROW_B);  // B-frag row base for this lane

    for (int t = 0; t < ITERS; t++) {
        const unsigned bo = (unsigned)((t & 1) ? BUF_B : 0);
        const unsigned bn = bo ^ (unsigned)BUF_B;

        // ---- issue next tile's global loads (latency hidden under compute) ----
        float4 zf[4];
        float2 kraw = {0.f, 0.f};
        if (t + 1 < ITERS) {
            const int nb1 = nbase + (t + 1) * BN;
            const float* zp = zb + (size_t)(nb1 + snq * 4) * DZ;
#pragma unroll
            for (int j = 0; j < 4; j++) zf[j] = *(const float4*)(zp + j * DZ);
            if (tid < BN) kraw = *(const float2*)(x + (size_t)(mb * N_TOT + nb1 + tid) * 2);
        }

        // ---- compute tile t from buffer bo ----
#pragma unroll
        for (int kc = 0; kc < 2; kc++) {
            const unsigned kb = bo + (unsigned)(kc * 128 + quad * 32);
            const float4 kxa = *(const float4*)(lds + kb + KX_OFS);
            const float4 kxb = *(const float4*)(lds + kb + KX_OFS + 16);
            const float4 kya = *(const float4*)(lds + kb + KY_OFS);
            const float4 kyb = *(const float4*)(lds + kb + KY_OFS + 16);
            const float4 hka = *(const float4*)(lds + kb + HK_OFS);
            const float4 hkb = *(const float4*)(lds + kb + HK_OFS + 16);
            const float kxr[8] = {kxa.x, kxa.y, kxa.z, kxa.w, kxb.x, kxb.y, kxb.z, kxb.w};
            const float kyr[8] = {kya.x, kya.y, kya.z, kya.w, kyb.x, kyb.y, kyb.z, kyb.w};
            const float hkr[8] = {hka.x, hka.y, hka.z, hka.w, hkb.x, hkb.y, hkb.z, hkb.w};

            // Weights for both row-groups, directly in A-frag layout.
            unsigned aw[2][4];
#pragma unroll
            for (int jp = 0; jp < 4; jp++) {
#pragma unroll
                for (int g = 0; g < 2; g++) {
                    const float s0 = fmaf(qxL[g], kxr[2 * jp],
                                      fmaf(qyL[g], kyr[2 * jp], hq[g] + hkr[2 * jp]));
                    const float s1 = fmaf(qxL[g], kxr[2 * jp + 1],
                                      fmaf(qyL[g], kyr[2 * jp + 1], hq[g] + hkr[2 * jp + 1]));
                    aw[g][jp] = pack_bf16_pair(__builtin_amdgcn_exp2f(s0),
                                               __builtin_amdgcn_exp2f(s1));
                }
            }
            const int4v  a0v = {(int)aw[0][0], (int)aw[0][1], (int)aw[0][2], (int)aw[0][3]};
            const int4v  a1v = {(int)aw[1][0], (int)aw[1][1], (int)aw[1][2], (int)aw[1][3]};
            const short8 af0 = __builtin_bit_cast(short8, a0v);
            const short8 af1 = __builtin_bit_cast(short8, a1v);

            // B-frags (shared by both row-groups) + 8 MFMA.
#pragma unroll
            for (int nt = 0; nt < 4; nt++) {
                const unsigned h  = (unsigned)(((nt & 1) * 4) | (l16 >> 2));
                const unsigned qp = ((unsigned)(kc * 4 + quad)) ^ h;
                const short8 bfrag =
                    *(const short8*)(lds + bo + rb_base + nt * (16 * ZROW_B) + qp * 16);
                acc[0][nt] = __builtin_amdgcn_mfma_f32_16x16x32_bf16(af0, bfrag, acc[0][nt], 0, 0, 0);
                acc[1][nt] = __builtin_amdgcn_mfma_f32_16x16x32_bf16(af1, bfrag, acc[1][nt], 0, 0, 0);
            }
        }

        // ---- stage next tile into buffer bn; single barrier per iteration ----
        if (t + 1 < ITERS) {
            stage(bn, zf, kraw);
            __syncthreads();
        }
    }

    // ---- epilogue: C/D layout col = lane&15 (dz), row = quad*4 + reg (g-row) ----
    // out pre-initialized to z_grid by init_out; both n-splits combine via atomics.
#pragma unroll
    for (int g = 0; g < 2; g++) {
        const int gout = gbase + wave * 32 + g * 16 + quad * 4;
#pragma unroll
        for (int nt = 0; nt < 4; nt++) {
#pragma unroll
            for (int r = 0; r < 4; r++) {
                const size_t idx = (size_t)(mb * G_TOT + gout + r) * DZ + nt * 16 + l16;
                atomicAdd(&out[idx], acc[g][nt][r]);
            }
        }
    }
}

extern "C" void kernel_launch(void* const* d_in, const int* in_sizes, int n_in,
                              void* d_out, int out_size, void* d_ws, size_t ws_size,
                              hipStream_t stream) {
    const float* x   = (const float*)d_in[0];
    const float* z   = (const float*)d_in[1];
    const float* xg  = (const float*)d_in[2];
    const float* zgr = (const float*)d_in[3];
    const float* lsp = (const float*)d_in[4];
    float* out = (float*)d_out;

    // out = z_grid via kernel (graph-friendly, ~3us vs ~60us SDMA memcpy)
    const int n4 = (M_TOT * G_TOT * DZ) / 4;  // 524288 float4s
    init_out<<<n4 / 256, 256, 0, stream>>>((const float4*)zgr, (float4*)out);

    dim3 grid(G_TOT / BG, M_TOT, NSPLIT);
    setconv_kernel<<<grid, THREADS, 0, stream>>>(x, z, xg, lsp, out);
}

// Round 4
// 122.616 us; speedup vs baseline: 1.5974x; 1.0260x over previous
//
#include <hip/hip_runtime.h>
#include <hip/hip_bf16.h>
#include <math.h>

// Problem constants (fixed by setup_inputs)
#define M_TOT 2
#define N_TOT 4096
#define DZ    64
#define G_TOT 16384

// Tiling: 256-thread blocks, 4 waves, each wave owns 32 g-rows (two A-frags).
#define BG      128
#define BN      64
#define THREADS 256
#define NSPLIT  4
#define NCHUNK  (N_TOT / NSPLIT)   // 1024
#define ITERS   (NCHUNK / BN)      // 16
// zT: bf16 [dz=64][n=64], row = 128 B. Full 3-bit XOR swizzle of the 16B block:
// phys_block = logical_block ^ ((row>>1)&7). Proven conflict-free for both the
// b64 staging writes (4 dwords/bank = b64 floor) and the b128 B-frag reads
// (8 dwords/bank = b128 floor). k-order inside 16B blocks preserved.
#define ZROW_B  128
#define ZT_B    (DZ * ZROW_B)      // 8192
#define KX_OFS  ZT_B               // 8192
#define KY_OFS  (KX_OFS + BN * 4)  // 8448
#define HK_OFS  (KY_OFS + BN * 4)  // 8704
#define BUF_B   (HK_OFS + BN * 4)  // 8960 bytes per pipeline buffer

typedef __attribute__((ext_vector_type(8))) short short8;  // 8 bf16 MFMA A/B frag
typedef __attribute__((ext_vector_type(4))) float f32x4;   // MFMA C/D frag
typedef __attribute__((ext_vector_type(4))) int   int4v;

#if __has_builtin(__builtin_amdgcn_cvt_pk_bf16_f32)
typedef __attribute__((ext_vector_type(2))) __bf16 bf16x2;
__device__ __forceinline__ unsigned int pack_bf16_pair(float lo, float hi) {
    return __builtin_bit_cast(unsigned int, __builtin_amdgcn_cvt_pk_bf16_f32(lo, hi));
}
#else
__device__ __forceinline__ unsigned int pack_bf16_pair(float lo, float hi) {
    const unsigned int a = __float_as_uint(lo) + 0x8000u;  // round-half-up to bf16
    const unsigned int b = __float_as_uint(hi) + 0x8000u;
    return __builtin_amdgcn_perm(b, a, 0x07060302u);       // [lo[31:16], hi[31:16]]
}
#endif

__global__ __launch_bounds__(THREADS, 4)
void setconv_kernel(const float* __restrict__ x,       // [2][4096][2]
                    const float* __restrict__ z,       // [2][4096][64]
                    const float* __restrict__ x_grid,  // [2][16384][2]
                    const float* __restrict__ z_grid,  // [2][16384][64]
                    const float* __restrict__ lsp,     // [2]
                    float* __restrict__ out)           // [2][16384][64], memset to 0
{
    __shared__ __align__(16) unsigned char lds[2 * BUF_B];

    const int tid  = threadIdx.x;
    const int wave = tid >> 6;
    const int lane = tid & 63;
    const int quad = lane >> 4;
    const int l16  = lane & 15;

    const int mb    = blockIdx.y;
    const int gbase = blockIdx.x * BG;
    const int nbase = blockIdx.z * NCHUNK;

    const float LOG2E = 1.44269504088896340736f;
    const float inv0 = 1.0f / (1e-5f + log1pf(__expf(lsp[0])));
    const float inv1 = 1.0f / (1e-5f + log1pf(__expf(lsp[1])));

    // Two row-groups per wave: rows wave*32 + {l16, 16+l16}.
    float qxL[2], qyL[2], hq[2];
#pragma unroll
    for (int g = 0; g < 2; g++) {
        const int grow = gbase + wave * 32 + g * 16 + l16;
        const float2 qraw = *(const float2*)&x_grid[(size_t)(mb * G_TOT + grow) * 2];
        const float qx = qraw.x * inv0, qy = qraw.y * inv1;
        qxL[g] = LOG2E * qx;
        qyL[g] = LOG2E * qy;
        hq[g]  = -0.5f * LOG2E * (qx * qx + qy * qy);
    }

    // Staging: sdzg = dz-group (consecutive lanes -> consecutive dz -> coalesced
    // float4 global loads), snq = n-quad (n = snq*4 + j).
    const int sdzg = tid & 15;
    const int snq  = tid >> 4;
    const float* zb = z + (size_t)mb * N_TOT * DZ + sdzg * 4;
    // Swizzled write bases (loop-invariant). Row d = sdzg*4 + i; swz(d) = (d>>1)&7
    // = (sdzg&3)*2 + (i>>1). Logical block = snq>>1, sub-offset = (snq&1)*8.
    const unsigned wrow  = (unsigned)(sdzg * 4) * ZROW_B + (unsigned)(snq & 1) * 8;
    const unsigned wb_lo = (unsigned)(((snq >> 1) ^ ((sdzg & 3) * 2 + 0)) & 7) * 16;  // i = 0,1
    const unsigned wb_hi = (unsigned)(((snq >> 1) ^ ((sdzg & 3) * 2 + 1)) & 7) * 16;  // i = 2,3

    // Swizzled read bases: row r = nt*16 + l16 -> swz = (l16>>1)&7 (nt*8 ≡ 0 mod 8);
    // block b = kc*4 + quad -> phys = (quad ^ swz) ^ (kc*4).
    const unsigned swz_l = (unsigned)((l16 >> 1) & 7);
    const unsigned q0    = (unsigned)quad ^ swz_l;
    const unsigned rbA   = (unsigned)l16 * ZROW_B + q0 * 16;         // kc = 0
    const unsigned rbB   = (unsigned)l16 * ZROW_B + (q0 ^ 4u) * 16;  // kc = 1

    f32x4 acc[2][4];
#pragma unroll
    for (int g = 0; g < 2; g++)
#pragma unroll
        for (int i = 0; i < 4; i++) acc[g][i] = (f32x4){0.f, 0.f, 0.f, 0.f};

    auto stage = [&](unsigned dst, const float4* zf, float2 kraw) {
        const float a0[4] = {zf[0].x, zf[0].y, zf[0].z, zf[0].w};
        const float a1[4] = {zf[1].x, zf[1].y, zf[1].z, zf[1].w};
        const float a2[4] = {zf[2].x, zf[2].y, zf[2].z, zf[2].w};
        const float a3[4] = {zf[3].x, zf[3].y, zf[3].z, zf[3].w};
#pragma unroll
        for (int i = 0; i < 4; i++) {
            uint2 w;
            w.x = pack_bf16_pair(a0[i], a1[i]);
            w.y = pack_bf16_pair(a2[i], a3[i]);
            const unsigned base = (i < 2) ? wb_lo : wb_hi;
            *(uint2*)(lds + dst + wrow + i * ZROW_B + base) = w;
        }
        if (tid < BN) {
            const float kx = kraw.x * inv0, ky = kraw.y * inv1;
            *(float*)(lds + dst + KX_OFS + tid * 4) = kx;
            *(float*)(lds + dst + KY_OFS + tid * 4) = ky;
            *(float*)(lds + dst + HK_OFS + tid * 4) = -0.5f * LOG2E * (kx * kx + ky * ky);
        }
    };

    // ---- prologue: fetch + stage tile 0 into buffer 0 ----
    {
        float4 zf[4];
        float2 kraw = {0.f, 0.f};
        const float* zp = zb + (size_t)(nbase + snq * 4) * DZ;
#pragma unroll
        for (int j = 0; j < 4; j++) zf[j] = *(const float4*)(zp + j * DZ);
        if (tid < BN) kraw = *(const float2*)(x + (size_t)(mb * N_TOT + nbase + tid) * 2);
        stage(0u, zf, kraw);
    }
    __syncthreads();

    for (int t = 0; t < ITERS; t++) {
        const unsigned bo = (unsigned)((t & 1) ? BUF_B : 0);
        const unsigned bn = bo ^ (unsigned)BUF_B;

        // ---- issue next tile's global loads (latency hidden under compute) ----
        float4 zf[4];
        float2 kraw = {0.f, 0.f};
        if (t + 1 < ITERS) {
            const int nb1 = nbase + (t + 1) * BN;
            const float* zp = zb + (size_t)(nb1 + snq * 4) * DZ;
#pragma unroll
            for (int j = 0; j < 4; j++) zf[j] = *(const float4*)(zp + j * DZ);
            if (tid < BN) kraw = *(const float2*)(x + (size_t)(mb * N_TOT + nb1 + tid) * 2);
        }

        // ---- compute tile t from buffer bo ----
#pragma unroll
        for (int kc = 0; kc < 2; kc++) {
            const unsigned kb = bo + (unsigned)(kc * 128 + quad * 32);
            const float4 kxa = *(const float4*)(lds + kb + KX_OFS);
            const float4 kxb = *(const float4*)(lds + kb + KX_OFS + 16);
            const float4 kya = *(const float4*)(lds + kb + KY_OFS);
            const float4 kyb = *(const float4*)(lds + kb + KY_OFS + 16);
            const float4 hka = *(const float4*)(lds + kb + HK_OFS);
            const float4 hkb = *(const float4*)(lds + kb + HK_OFS + 16);
            const float kxr[8] = {kxa.x, kxa.y, kxa.z, kxa.w, kxb.x, kxb.y, kxb.z, kxb.w};
            const float kyr[8] = {kya.x, kya.y, kya.z, kya.w, kyb.x, kyb.y, kyb.z, kyb.w};
            const float hkr[8] = {hka.x, hka.y, hka.z, hka.w, hkb.x, hkb.y, hkb.z, hkb.w};

            // Weights for both row-groups, directly in A-frag layout.
            unsigned aw[2][4];
#pragma unroll
            for (int jp = 0; jp < 4; jp++) {
#pragma unroll
                for (int g = 0; g < 2; g++) {
                    const float s0 = fmaf(qxL[g], kxr[2 * jp],
                                      fmaf(qyL[g], kyr[2 * jp], hq[g] + hkr[2 * jp]));
                    const float s1 = fmaf(qxL[g], kxr[2 * jp + 1],
                                      fmaf(qyL[g], kyr[2 * jp + 1], hq[g] + hkr[2 * jp + 1]));
                    aw[g][jp] = pack_bf16_pair(__builtin_amdgcn_exp2f(s0),
                                               __builtin_amdgcn_exp2f(s1));
                }
            }
            const int4v  a0v = {(int)aw[0][0], (int)aw[0][1], (int)aw[0][2], (int)aw[0][3]};
            const int4v  a1v = {(int)aw[1][0], (int)aw[1][1], (int)aw[1][2], (int)aw[1][3]};
            const short8 af0 = __builtin_bit_cast(short8, a0v);
            const short8 af1 = __builtin_bit_cast(short8, a1v);

            // B-frags (shared by both row-groups) + 8 MFMA.
            const unsigned rb = bo + ((kc == 0) ? rbA : rbB);
#pragma unroll
            for (int nt = 0; nt < 4; nt++) {
                const short8 bfrag = *(const short8*)(lds + rb + nt * (16 * ZROW_B));
                acc[0][nt] = __builtin_amdgcn_mfma_f32_16x16x32_bf16(af0, bfrag, acc[0][nt], 0, 0, 0);
                acc[1][nt] = __builtin_amdgcn_mfma_f32_16x16x32_bf16(af1, bfrag, acc[1][nt], 0, 0, 0);
            }
        }

        // ---- stage next tile into buffer bn; single barrier per iteration ----
        if (t + 1 < ITERS) {
            stage(bn, zf, kraw);
            __syncthreads();
        }
    }

    // ---- epilogue: C/D layout col = lane&15 (dz), row = quad*4 + reg (g-row) ----
    // out was memset to 0; all 4 n-splits atomicAdd. Split 0 folds z_grid in.
    const bool add_zg = (blockIdx.z == 0);
#pragma unroll
    for (int g = 0; g < 2; g++) {
        const int gout = gbase + wave * 32 + g * 16 + quad * 4;
#pragma unroll
        for (int nt = 0; nt < 4; nt++) {
#pragma unroll
            for (int r = 0; r < 4; r++) {
                const size_t idx = (size_t)(mb * G_TOT + gout + r) * DZ + nt * 16 + l16;
                const float v = add_zg ? (acc[g][nt][r] + z_grid[idx]) : acc[g][nt][r];
                atomicAdd(&out[idx], v);
            }
        }
    }
}

extern "C" void kernel_launch(void* const* d_in, const int* in_sizes, int n_in,
                              void* d_out, int out_size, void* d_ws, size_t ws_size,
                              hipStream_t stream) {
    const float* x   = (const float*)d_in[0];
    const float* z   = (const float*)d_in[1];
    const float* xg  = (const float*)d_in[2];
    const float* zgr = (const float*)d_in[3];
    const float* lsp = (const float*)d_in[4];
    float* out = (float*)d_out;

    // out = 0 (write-only memset node; z_grid folded in by split 0's atomics)
    hipMemsetAsync(out, 0, sizeof(float) * (size_t)M_TOT * G_TOT * DZ, stream);

    dim3 grid(G_TOT / BG, M_TOT, NSPLIT);
    setconv_kernel<<<grid, THREADS, 0, stream>>>(x, z, xg, zgr, lsp, out);
}